// Round 10
// baseline (37.255 us; speedup 1.0000x reference)
//
#include <hip/hip_runtime.h>
#include <hip/hip_fp16.h>
#include <math.h>

#define IN_DIM 256
#define L1_DIM 16
#define N_ETYPE_MAX 1000

typedef _Float16 f16x8 __attribute__((ext_vector_type(8)));
typedef float f32x4 __attribute__((ext_vector_type(4)));

// ---------------- convert kernel ----------------
// Builds (a) interleaved fp16 level-2 table wq[t] = [w1_l2[t] | w2_l2[t]],
// (b) fragment-ordered fp16 level-1 tables wf[s][q][r][j] = w[(32s+8q+j)][r]
// so proj's B-preload is 16 coalesced 16B loads per lane (no scalar gather,
// no per-wave f32->f16 conversion).
__global__ __launch_bounds__(256) void convert_kernel(
    const float* __restrict__ w1_l1,  // [256][16]
    const float* __restrict__ w2_l1,
    const float* __restrict__ w1_l2,  // [1000][16]
    const float* __restrict__ w2_l2,
    __half* __restrict__ wq,          // [n_types][32]
    __half* __restrict__ wf1,         // [4096] fragment-ordered
    __half* __restrict__ wf2,
    int n_l2) {
  int idx = (int)blockIdx.x * 256 + (int)threadIdx.x;
  if (idx < n_l2) {
    int t = idx >> 4;
    int j = idx & 15;
    wq[t * 32 + j]      = __float2half(w1_l2[idx]);
    wq[t * 32 + 16 + j] = __float2half(w2_l2[idx]);
  }
  if (idx < IN_DIM * L1_DIM) {   // 4096
    int j = idx & 7;
    int rest = idx >> 3;
    int r = rest & 15;
    rest >>= 4;
    int q = rest & 3;
    int s = rest >> 2;
    int k = 32 * s + 8 * q + j;
    wf1[idx] = __float2half(w1_l1[k * L1_DIM + r]);
    wf2[idx] = __float2half(w2_l1[k * L1_DIM + r]);
  }
}

// ---------------- proj kernel (MFMA f16) ----------------
// GEMM M=n_nodes, N=32 ([w1|w2]), K=256 via mfma_f32_16x16x32_f16.
// Block = 256 = 4 waves, M=64 nodes/block, wave w owns rows 16w..16w+15.
// No LDS, no barrier. B fragments loaded from the fragment-ordered fp16
// tables: 16 fully-coalesced 16B loads per lane (1 KB/instruction).
__global__ __launch_bounds__(256) void proj_kernel(
    const float* __restrict__ z,
    const __half* __restrict__ wf1,   // fragment-ordered [s][q][r][8]
    const __half* __restrict__ wf2,
    __half* __restrict__ h1,          // [n_nodes][16] fp16
    __half* __restrict__ h2,
    int n_nodes) {
  const int tid  = (int)threadIdx.x;
  const int lane = tid & 63;
  const int wv   = tid >> 6;      // 0..3
  const int r    = lane & 15;     // A row-in-tile / B col / D col
  const int q    = lane >> 4;     // k-subgroup 0..3
  const int node0 = (int)blockIdx.x * 64;

  // ---- B fragments: one 16B coalesced load per s per table ----
  const f16x8* wf1v = reinterpret_cast<const f16x8*>(wf1);
  const f16x8* wf2v = reinterpret_cast<const f16x8*>(wf2);
  f16x8 bf1[8], bf2[8];
#pragma unroll
  for (int s = 0; s < 8; ++s) {
    int f = (s * 4 + q) * 16 + r;     // addr = lane*16B + s*1024B
    bf1[s] = wf1v[f];
    bf2[s] = wf2v[f];
  }

  // ---- A row pointer (clamped for tail block) ----
  int arow = node0 + wv * 16 + r;
  int ar = arow < n_nodes ? arow : (n_nodes - 1);
  const float* zrow = z + (size_t)ar * IN_DIM + 8 * q;

  f32x4 acc1 = {0.f, 0.f, 0.f, 0.f};
  f32x4 acc2 = {0.f, 0.f, 0.f, 0.f};

#pragma unroll
  for (int s = 0; s < 8; ++s) {
    float4 lo = *reinterpret_cast<const float4*>(zrow + 32 * s);
    float4 hi = *reinterpret_cast<const float4*>(zrow + 32 * s + 4);
    f16x8 af;
    af[0] = (_Float16)lo.x; af[1] = (_Float16)lo.y;
    af[2] = (_Float16)lo.z; af[3] = (_Float16)lo.w;
    af[4] = (_Float16)hi.x; af[5] = (_Float16)hi.y;
    af[6] = (_Float16)hi.z; af[7] = (_Float16)hi.w;
    acc1 = __builtin_amdgcn_mfma_f32_16x16x32_f16(af, bf1[s], acc1, 0, 0, 0);
    acc2 = __builtin_amdgcn_mfma_f32_16x16x32_f16(af, bf2[s], acc2, 0, 0, 0);
  }

  // ---- D layout: col = r, row = 4q + i -> node = node0 + 16wv + 4q + i ----
#pragma unroll
  for (int i = 0; i < 4; ++i) {
    int node = node0 + wv * 16 + 4 * q + i;
    if (node < n_nodes) {
      h1[(size_t)node * L1_DIM + r] = __float2half(fmaxf(acc1[i], 0.f));
      h2[(size_t)node * L1_DIM + r] = __float2half(fmaxf(acc2[i], 0.f));
    }
  }
}

// ---------------- edge kernel (R8 structure) ----------------
// 2 lanes per edge (q = tid&1 owns row-half q). Per lane: 2 VMEM gathers
// (h1[src], h2[dst] halves — one instr covers a whole 32B row across the
// wave) + 2 ds_read_b128 from the LDS-staged interleaved w table (off the
// VMEM port). 8x fdot2, shfl_xor(1), even lane stores sigmoid.
union F4H { float4 f; __half2 h[4]; };

__global__ __launch_bounds__(512) void edge_kernel(
    const int* __restrict__ edge_index,  // [2][n_edges]
    const int* __restrict__ edge_type,   // [n_edges]
    const __half* __restrict__ h1,
    const __half* __restrict__ h2,
    const __half* __restrict__ wq,       // [1000][32] interleaved fp16
    float* __restrict__ out,
    int n_edges, int n_types) {
  __shared__ __align__(16) __half wl[N_ETYPE_MAX * 32];  // 62.5 KB

  const int tid = (int)threadIdx.x;

  // stage interleaved w table: coalesced float4 copies
  {
    const float4* srcp = reinterpret_cast<const float4*>(wq);
    float4* dstp = reinterpret_cast<float4*>(wl);
    int nf4 = n_types * 4;  // 32 halves = 4 float4 per type
    for (int i = tid; i < nf4; i += 512) dstp[i] = srcp[i];
  }
  __syncthreads();

  const int q = tid & 1;
  const int pair = tid >> 1;          // 0..255
  const int stride = (int)gridDim.x * 256;

  for (int e = (int)blockIdx.x * 256 + pair; e < n_edges; e += stride) {
    int src = edge_index[e];
    int dst = edge_index[n_edges + e];
    int t   = edge_type[e];

    F4H a, b, u, v;
    a.f = *reinterpret_cast<const float4*>(h1 + (size_t)src * L1_DIM + q * 8);
    b.f = *reinterpret_cast<const float4*>(h2 + (size_t)dst * L1_DIM + q * 8);
    u.f = *reinterpret_cast<const float4*>(wl + t * 32 + q * 8);
    v.f = *reinterpret_cast<const float4*>(wl + t * 32 + 16 + q * 8);

    float s = 0.f;
#if __has_builtin(__builtin_amdgcn_fdot2)
#pragma unroll
    for (int p = 0; p < 4; ++p) {
      s = __builtin_amdgcn_fdot2(a.h[p], u.h[p], s, false);
      s = __builtin_amdgcn_fdot2(b.h[p], v.h[p], s, false);
    }
#else
#pragma unroll
    for (int p = 0; p < 4; ++p) {
      float2 af = __half22float2(a.h[p]), uf = __half22float2(u.h[p]);
      float2 bf = __half22float2(b.h[p]), vf = __half22float2(v.h[p]);
      s = fmaf(af.x, uf.x, s); s = fmaf(af.y, uf.y, s);
      s = fmaf(bf.x, vf.x, s); s = fmaf(bf.y, vf.y, s);
    }
#endif

    s += __shfl_xor(s, 1);
    if (q == 0) {
      out[e] = 1.0f / (1.0f + __expf(-s));
    }
  }
}

extern "C" void kernel_launch(void* const* d_in, const int* in_sizes, int n_in,
                              void* d_out, int out_size, void* d_ws, size_t ws_size,
                              hipStream_t stream) {
  const float* z      = (const float*)d_in[0];
  const int* edge_idx = (const int*)d_in[1];
  const int* edge_typ = (const int*)d_in[2];
  const float* w1_l1  = (const float*)d_in[3];
  const float* w1_l2  = (const float*)d_in[4];
  const float* w2_l1  = (const float*)d_in[5];
  const float* w2_l2  = (const float*)d_in[6];
  float* out = (float*)d_out;

  int n_nodes = in_sizes[0] / IN_DIM;
  int n_edges = in_sizes[2];
  int n_l2    = in_sizes[4];          // 1000*16
  int n_types = n_l2 / L1_DIM;        // 1000

  __half* h1  = (__half*)d_ws;
  __half* h2  = h1 + (size_t)n_nodes * L1_DIM;
  __half* wq  = h2 + (size_t)n_nodes * L1_DIM;     // [n_types][32]
  __half* wf1 = wq + (size_t)n_types * 32;         // [4096]
  __half* wf2 = wf1 + IN_DIM * L1_DIM;             // [4096]

  {
    int grid = (n_l2 + 255) / 256;   // covers 16000 > 4096
    convert_kernel<<<grid, 256, 0, stream>>>(w1_l1, w2_l1, w1_l2, w2_l2,
                                             wq, wf1, wf2, n_l2);
  }
  {
    int grid = (n_nodes + 63) / 64;  // 782
    proj_kernel<<<grid, 256, 0, stream>>>(z, wf1, wf2, h1, h2, n_nodes);
  }
  {
    edge_kernel<<<512, 512, 0, stream>>>(edge_idx, edge_typ, h1, h2, wq,
                                         out, n_edges, n_types);
  }
}